// Round 10
// baseline (85.069 us; speedup 1.0000x reference)
//
#include <hip/hip_runtime.h>
#include <hip/hip_bf16.h>

using f32x4 = __attribute__((ext_vector_type(4))) float;
using s16x8 = __attribute__((ext_vector_type(8))) short;

constexpr int KDIM = 768;
constexpr int NDIM = 768;
constexpr int BM = 128;
constexpr int BN = 256;
constexpr int BK = 64;
constexpr int NBN = NDIM / BN;  // 3
constexpr int NT = KDIM / BK;   // 12 K-steps

__device__ __forceinline__ unsigned short f2bf(float f) {
    __bf16 h = (__bf16)f;       // pairs lower to v_cvt_pk_bf16_f32
    return __builtin_bit_cast(unsigned short, h);
}

__device__ __forceinline__ short sgnbf(float w) {
    unsigned u = __builtin_bit_cast(unsigned, w);
    return (w != 0.f) ? (short)(unsigned short)(0x3F80u | ((u >> 16) & 0x8000u))
                      : (short)0;
}

__device__ __forceinline__ s16x8 cvt8(float4 u, float4 v) {
    s16x8 c;
    c[0] = (short)f2bf(u.x); c[1] = (short)f2bf(u.y);
    c[2] = (short)f2bf(u.z); c[3] = (short)f2bf(u.w);
    c[4] = (short)f2bf(v.x); c[5] = (short)f2bf(v.y);
    c[6] = (short)f2bf(v.z); c[7] = (short)f2bf(v.w);
    return c;
}

// Fragment-ordered W for (kt64, bn256): 2048 slots x 16 B = 32 KB per chunk.
// slot = (kk*16 + n16)*64 + lane; element j:
//   col = bn*256 + n16*16 + (lane&15), k = kt*64 + kk*32 + (lane>>4)*8 + j
__global__ void binarize_w(const float* __restrict__ W, unsigned short* __restrict__ Wf) {
    const int g = blockIdx.x * 256 + threadIdx.x;   // 12*3*2048 = 73728 threads
    const int lane  = g & 63;
    const int sg    = g >> 6;
    const int srow  = sg & 31;        // kk*16 + n16
    const int chunk = sg >> 5;        // kt*3 + bn
    const int bn = chunk % NBN;
    const int kt = chunk / NBN;
    const int kk  = srow >> 4;
    const int n16 = srow & 15;
    const int col = bn * 256 + n16 * 16 + (lane & 15);
    const int k0  = kt * 64 + kk * 32 + (lane >> 4) * 8;
    const float* src = W + (size_t)col * KDIM + k0;
    s16x8 r;
    #pragma unroll
    for (int j = 0; j < 8; ++j) r[j] = sgnbf(src[j]);
    *(s16x8*)(Wf + (size_t)g * 8) = r;
}

// One phase: {2 ds_read A-frags; staging-issue EXTRA} barrier; prio; 8 MFMA;
// prio; barrier.  All acc/B indices compile-time (rule #20).
#define PHASE(C, KK, MB, BARR, ...) do {                                       \
    s16x8 af0_ = *(const s16x8*)&As[C][(size_t)(((KK)*8 + wr4 + (MB)) * 64 + lane) * 8];       \
    s16x8 af1_ = *(const s16x8*)&As[C][(size_t)(((KK)*8 + wr4 + (MB) + 1) * 64 + lane) * 8];   \
    __VA_ARGS__;                                                               \
    __builtin_amdgcn_s_barrier();                                              \
    __builtin_amdgcn_s_setprio(1);                                             \
    _Pragma("unroll")                                                          \
    for (int n_ = 0; n_ < 4; ++n_) {                                           \
        acc[MB][n_]     = __builtin_amdgcn_mfma_f32_16x16x32_bf16(af0_, BARR[KK][n_], acc[MB][n_], 0, 0, 0);       \
        acc[(MB)+1][n_] = __builtin_amdgcn_mfma_f32_16x16x32_bf16(af1_, BARR[KK][n_], acc[(MB)+1][n_], 0, 0, 0);   \
    }                                                                          \
    __builtin_amdgcn_s_setprio(0);                                             \
    __builtin_amdgcn_s_barrier();                                              \
} while (0)

// 4-phase K-step: ph0 issues A(kt+1), ph1 issues B(kt+1), ph3 writes A(kt+1).
// Steady-state vmcnt is counted (8/4), never drained (T4).
#define KSTEP(C, BCUR, BNXT, KT, PF) do {                                      \
    PHASE(C, 0, 0, BCUR, { if (PF) loadA((KT) + 1, aR); });                    \
    PHASE(C, 0, 2, BCUR, { if (PF) loadB((KT) + 1, BNXT); });                  \
    PHASE(C, 1, 0, BCUR, {});                                                  \
    PHASE(C, 1, 2, BCUR, {                                                     \
        if (PF) writeA((C) ^ 1, aR);                                           \
        asm volatile("s_waitcnt lgkmcnt(0)" ::: "memory");                     \
        __builtin_amdgcn_sched_barrier(0);                                     \
    });                                                                        \
} while (0)

// A LDS: fragment-ordered, slot = (kk*8 + sub16)*64 + lane, 1024 slots x 16 B
// = 16 KB per buffer (double-buffered, 32 KB total).
template<bool PRE>
__global__ __launch_bounds__(512, 2)
void binlin_mfma(const float* __restrict__ X, const float* __restrict__ W,
                 const unsigned short* __restrict__ Wf, float* __restrict__ Out) {
    __shared__ __align__(16) unsigned short As[2][1024 * 8];   // 2 x 16 KB

    const int bid = blockIdx.x;
    const int cpx = gridDim.x >> 3;                 // 768 % 8 == 0 -> bijective
    const int swz = (bid & 7) * cpx + (bid >> 3);   // same-XCD chunks; bn fastest
    const int bm = swz / NBN;
    const int bn = swz - bm * NBN;

    const int t    = threadIdx.x;
    const int lane = t & 63;
    const int wid  = t >> 6;          // 8 waves: 2 (wr) x 4 (wc)
    const int wr   = wid >> 2;
    const int wc   = wid & 3;
    const int wm   = wr * 64;
    const int wn   = wc * 64;
    const int wr4  = wr * 4;

    const float* Xb = X + (size_t)bm * BM * KDIM;

    // ---- A staging: thread t reads row r = t>>2, k-chunks (t&3)*8 and +32;
    // adjacent lane quads cover contiguous 128 B per row (R6 coalescing).
    const int r  = t >> 2;
    const int q  = t & 3;
    const float* Abase = Xb + (size_t)r * KDIM + q * 8;
    const int sA0 = ((r >> 4)) * 64 + (r & 15) + 16 * q;        // kk0 slot
    const int sA1 = (8 + (r >> 4)) * 64 + (r & 15) + 16 * q;    // kk1 slot

    float4 aR[4];
    auto loadA = [&](int kt, float4 a[4]) {
        const float* p = Abase + kt * BK;
        a[0] = *(const float4*)p;
        a[1] = *(const float4*)(p + 4);
        a[2] = *(const float4*)(p + 32);
        a[3] = *(const float4*)(p + 36);
    };
    auto writeA = [&](int buf, float4 a[4]) {
        *(s16x8*)&As[buf][(size_t)sA0 * 8] = cvt8(a[0], a[1]);
        *(s16x8*)&As[buf][(size_t)sA1 * 8] = cvt8(a[2], a[3]);
    };
    // ---- B: fragment-ordered Wf -> registers (L2/L1-resident, no LDS)
    auto loadB = [&](int kt, s16x8 b[2][4]) {
        if constexpr (PRE) {
            const unsigned short* base = Wf + (size_t)(kt * NBN + bn) * 2048 * 8;
            #pragma unroll
            for (int kk = 0; kk < 2; ++kk)
                #pragma unroll
                for (int n = 0; n < 4; ++n)
                    b[kk][n] = *(const s16x8*)(base + (size_t)((kk * 16 + wc * 4 + n) * 64 + lane) * 8);
        } else {
            #pragma unroll
            for (int kk = 0; kk < 2; ++kk)
                #pragma unroll
                for (int n = 0; n < 4; ++n) {
                    const int col = bn * 256 + (wc * 4 + n) * 16 + (lane & 15);
                    const int k0  = kt * 64 + kk * 32 + (lane >> 4) * 8;
                    const float* wp = W + (size_t)col * KDIM + k0;
                    float4 u = *(const float4*)wp;
                    float4 v = *(const float4*)(wp + 4);
                    s16x8 c;
                    c[0] = sgnbf(u.x); c[1] = sgnbf(u.y); c[2] = sgnbf(u.z); c[3] = sgnbf(u.w);
                    c[4] = sgnbf(v.x); c[5] = sgnbf(v.y); c[6] = sgnbf(v.z); c[7] = sgnbf(v.w);
                    b[kk][n] = c;
                }
        }
    };

    f32x4 acc[4][4] = {};
    s16x8 B0[2][4], B1[2][4];

    // ---- prologue ----
    loadA(0, aR);
    writeA(0, aR);                  // vmcnt wait on aR only
    loadB(0, B0);                   // 8 loads stay outstanding
    asm volatile("s_waitcnt lgkmcnt(0)" ::: "memory");
    __builtin_amdgcn_s_barrier();

    // ---- main: 12 K-steps, buffers/regs by static parity ----
    for (int kt2 = 0; kt2 < 5; ++kt2) {
        const int kt = 2 * kt2;
        KSTEP(0, B0, B1, kt, true);
        KSTEP(1, B1, B0, kt + 1, true);
    }
    KSTEP(0, B0, B1, 10, true);
    KSTEP(1, B1, B0, 11, false);

    // ---- epilogue: C/D layout col = lane&15, row = (lane>>4)*4 + reg ----
    float* Ob = Out + (size_t)(bm * BM) * NDIM + (size_t)bn * BN;
    const int lr = lane & 15;
    #pragma unroll
    for (int m = 0; m < 4; ++m) {
        const int row0 = wm + m * 16 + (lane >> 4) * 4;
        #pragma unroll
        for (int n = 0; n < 4; ++n) {
            const int col = wn + n * 16 + lr;
            #pragma unroll
            for (int rr = 0; rr < 4; ++rr)
                Ob[(size_t)(row0 + rr) * NDIM + col] = acc[m][n][rr];
        }
    }
}

extern "C" void kernel_launch(void* const* d_in, const int* in_sizes, int n_in,
                              void* d_out, int out_size, void* d_ws, size_t ws_size,
                              hipStream_t stream) {
    const float* X = (const float*)d_in[0];
    const float* W = (const float*)d_in[1];
    float* Out = (float*)d_out;
    const int M = in_sizes[0] / KDIM;                  // 32768
    const int grid = (M / BM) * NBN;                   // 256 * 3 = 768
    const size_t need = (size_t)NDIM * KDIM * sizeof(unsigned short);  // 1.125 MB

    if (ws_size >= need) {
        unsigned short* Wf = (unsigned short*)d_ws;
        binarize_w<<<(NT * NBN * 2048) / 256, 256, 0, stream>>>(W, Wf);
        binlin_mfma<true><<<grid, 512, 0, stream>>>(X, W, Wf, Out);
    } else {
        binlin_mfma<false><<<grid, 512, 0, stream>>>(X, W, nullptr, Out);
    }
}